// Round 15
// baseline (34.523 us; speedup 1.0000x reference)
//
#include <hip/hip_runtime.h>
#include <stdint.h>

// MPS amplitude via MFMA, round 15: MERGED DUAL CHAINS (ILP over TLP).
// 256 blocks x 256 thr, 32 elements/block. Each wave (nt x cg role) processes
// TWO independent 16-element chains per step, sharing ONE register copy of
// the P fragments (halves P VMEM/CU; step skeleton paid once per 2 chains;
// two independent dep chains give in-wave ILP that 2-block TLP never gave).
// fp16 1-term P and V (RTNE), pair products scaled 2^-(p&1) (epilogue 2^15),
// 31 steps, lgkm-only barriers. Pairbuild identical to R12-R14.

typedef __attribute__((ext_vector_type(4))) float        f32x4;
typedef __attribute__((ext_vector_type(8))) _Float16     f16x8;
typedef __attribute__((ext_vector_type(4))) unsigned int u32x4;

__device__ __forceinline__ float f16lo(unsigned u) {
    return (float)__builtin_bit_cast(_Float16, (unsigned short)(u & 0xFFFFu));
}
__device__ __forceinline__ float f16hi(unsigned u) {
    return (float)__builtin_bit_cast(_Float16, (unsigned short)(u >> 16));
}
__device__ __forceinline__ unsigned pk_rtne(float a, float b) {
    unsigned short x = __builtin_bit_cast(unsigned short, (_Float16)a);
    unsigned short y = __builtin_bit_cast(unsigned short, (_Float16)b);
    return (unsigned)x | ((unsigned)y << 16);
}
__device__ __forceinline__ f16x8 frg16(u32x4 x) { return __builtin_bit_cast(f16x8, x); }
#define MFMAH(A, B, C) __builtin_amdgcn_mfma_f32_16x16x32_f16(frg16(A), frg16(B), C, 0, 0, 0)

// storage permutation: complex column u -> fragment word slot
__device__ __forceinline__ int qperm(int u) {
    return (u >> 4) * 16 + ((u >> 1) & 3) * 4 + ((u >> 3) & 1) * 2 + (u & 1);
}

// ---------------- pair-product build (one-time, 124 blocks) ----------------
// ws (u32 words): pair stride 4096 (16KB). word at p*4096 + c*1024 + off,
// off = kk*512 + g*128 + col*4 + q, matrix row i = kk*16 + 2g + (q&1) + 8*(q>>1).
__global__ __launch_bounds__(256, 1) void mps_pairbuild(
    const float* __restrict__ bulk_r, const float* __restrict__ bulk_i,
    unsigned* __restrict__ ws)
{
    const int bx = blockIdx.x;
    const int p  = bx >> 2;            // pair 0..30
    const int c  = bx & 3;             // combo = s1 + 2*s2
    const int s1 = c & 1, s2 = c >> 1;
    const float* A1r = bulk_r + ((size_t)(2 * p)     * 2 + s1) * 1024;
    const float* A1i = bulk_i + ((size_t)(2 * p)     * 2 + s1) * 1024;
    const float* A2r = bulk_r + ((size_t)(2 * p + 1) * 2 + s2) * 1024;
    const float* A2i = bulk_i + ((size_t)(2 * p + 1) * 2 + s2) * 1024;

    __shared__ float s1r[1024], s1i[1024], s2r[1024], s2i[1024];
    for (int k = threadIdx.x; k < 1024; k += 256) {
        s1r[k] = A1r[k]; s1i[k] = A1i[k];
        s2r[k] = A2r[k]; s2i[k] = A2i[k];
    }
    __syncthreads();

    const int i  = threadIdx.x >> 3;        // P row 0..31
    const int j0 = (threadIdx.x & 7) * 4;   // 4 output columns
    float pr[4] = {0,0,0,0}, pi[4] = {0,0,0,0};
    #pragma unroll 4
    for (int k = 0; k < 32; ++k) {
        const float ar = s1r[i * 32 + k], ai = s1i[i * 32 + k];
        #pragma unroll
        for (int d = 0; d < 4; ++d) {
            const float br = s2r[k * 32 + j0 + d], bi = s2i[k * 32 + j0 + d];
            pr[d] += ar * br - ai * bi;
            pi[d] += ar * bi + ai * br;
        }
    }

    unsigned* wsu = ws + (size_t)p * 4096 + (size_t)c * 1024;
    const int kk = i >> 4;
    const int i4 = i & 15;
    const int qq = (i4 & 1) | (((i4 >> 3) & 1) << 1);
    const int g  = (i4 >> 1) & 3;
    const float sc = (p & 1) ? 0.5f : 1.0f;   // exact 2^-(p&1)
    #pragma unroll
    for (int d = 0; d < 4; ++d) {
        const int off = kk * 512 + g * 128 + (j0 + d) * 4 + qq;
        wsu[off] = pk_rtne(pr[d] * sc, pi[d] * sc);
    }
}

// ---------------- main chain kernel (31 pair-steps, dual chains) ----------
__global__ __launch_bounds__(256) void mps_pair16m_kernel(
    const int*   __restrict__ spin,
    const float* __restrict__ left_r,  const float* __restrict__ left_i,
    const float* __restrict__ right_r, const float* __restrict__ right_i,
    const unsigned* __restrict__ ws,
    float2*      __restrict__ out)
{
    __shared__ unsigned Vst[2][32 * 36];   // [buf][e*36 + slot], e 0..31
    __shared__ float2 red[32][8];
    __shared__ unsigned smask[32][2];

    const int tid  = threadIdx.x;
    const int l    = tid & 63;
    const int wid  = tid >> 6;            // 0..3
    const int nt   = wid >> 1;            // column half
    const int cg   = wid & 1;             // s2 value this wave owns
    const int lr16 = l & 15;
    const int lg   = l >> 4;
    const int jc   = nt * 16 + lr16;      // C column (j)
    const int qjc  = qperm(jc);
    const int e0   = blockIdx.x * 32;

    // ---- spin masks (32 elements) ----
    if (tid < 32) {
        const int* sp = spin + (size_t)(e0 + tid) * 64;
        unsigned a0 = 0, a1 = 0;
        #pragma unroll
        for (int k = 0; k < 32; ++k) a0 |= (unsigned)(sp[k] & 1) << k;
        #pragma unroll
        for (int k = 0; k < 32; ++k) a1 |= (unsigned)(sp[32 + k] & 1) << k;
        smask[tid][0] = a0; smask[tid][1] = a1;
    }

    // ---- init v = left[s0] as packed fp16 (q-permuted), 32 elements ----
    {
        const int e  = tid & 31;
        const int j0 = (tid >> 5) * 4;    // 0..28
        const int s0 = spin[(size_t)(e0 + e) * 64] & 1;
        #pragma unroll
        for (int d = 0; d < 4; ++d) {
            const int j  = j0 + d;
            Vst[0][e * 36 + qperm(j)] =
                pk_rtne(left_r[s0 * 32 + j], left_i[s0 * 32 + j]);
        }
    }

    // ---- issue pair-0 P-fragment loads: P[s1][kk] (shared by both chains) --
    const unsigned* pbw = ws + (size_t)(2 * cg) * 1024 + lg * 128 + jc * 4;
    u32x4 PA[2][2], PB[2][2];
    #pragma unroll
    for (int s1 = 0; s1 < 2; ++s1)
        #pragma unroll
        for (int kk = 0; kk < 2; ++kk)
            PA[s1][kk] = *(const u32x4*)(pbw + s1 * 1024 + kk * 512);

    __syncthreads();

    // per-lane spin words: chain0 rows lg*4+r, chain1 rows 16+lg*4+r
    unsigned em0a[4], em1a[4], em0b[4], em1b[4];
    #pragma unroll
    for (int r = 0; r < 4; ++r) {
        em0a[r] = smask[lg * 4 + r][0];
        em1a[r] = smask[lg * 4 + r][1];
        em0b[r] = smask[16 + lg * 4 + r][0];
        em1b[r] = smask[16 + lg * 4 + r][1];
    }

    auto step = [&](int t, const unsigned* Vin, unsigned* Vout,
                    u32x4 (&Pc)[2][2], u32x4 (&Pn)[2][2]) {
        // prefetch next pair's P fragments (shared)
        {
            int tn = t + 1; if (tn > 30) tn = 30;
            const unsigned* pb = ws + (size_t)tn * 4096 + (size_t)(2 * cg) * 1024
                               + lg * 128 + jc * 4;
            #pragma unroll
            for (int s1 = 0; s1 < 2; ++s1)
                #pragma unroll
                for (int kk = 0; kk < 2; ++kk)
                    Pn[s1][kk] = *(const u32x4*)(pb + s1 * 1024 + kk * 512);
        }

        // V fragment reads for both chains (4 x ds_read_b128)
        const unsigned* pva = Vin + lr16 * 36 + 4 * lg;          // chain 0
        const unsigned* pvb = pva + 16 * 36;                     // chain 1
        u32x4 Va0 = *(const u32x4*)(pva);
        u32x4 Va1 = *(const u32x4*)(pva + 16);
        u32x4 Vb0 = *(const u32x4*)(pvb);
        u32x4 Vb1 = *(const u32x4*)(pvb + 16);

        // derive V_r = (vr,-vi) and V_i = (vi,vr) for both chains
        u32x4 ra0, ra1, ia0, ia1, rb0, rb1, ib0, ib1;
        #pragma unroll
        for (int q = 0; q < 4; ++q) {
            ra0[q] = Va0[q] ^ 0x80000000u;
            ra1[q] = Va1[q] ^ 0x80000000u;
            rb0[q] = Vb0[q] ^ 0x80000000u;
            rb1[q] = Vb1[q] ^ 0x80000000u;
            ia0[q] = __builtin_amdgcn_alignbit(Va0[q], Va0[q], 16);
            ia1[q] = __builtin_amdgcn_alignbit(Va1[q], Va1[q], 16);
            ib0[q] = __builtin_amdgcn_alignbit(Vb0[q], Vb0[q], 16);
            ib1[q] = __builtin_amdgcn_alignbit(Vb1[q], Vb1[q], 16);
        }

        // 16 MFMAs: 2 chains x 2 s1-combos x 2 kk x {R,I} (8 indep 2-chains)
        f32x4 aR0 = {0,0,0,0}, aI0 = {0,0,0,0}, aR1 = {0,0,0,0}, aI1 = {0,0,0,0};
        f32x4 bR0 = {0,0,0,0}, bI0 = {0,0,0,0}, bR1 = {0,0,0,0}, bI1 = {0,0,0,0};
        aR0 = MFMAH(ra0, Pc[0][0], aR0); aR0 = MFMAH(ra1, Pc[0][1], aR0);
        bR0 = MFMAH(rb0, Pc[0][0], bR0); bR0 = MFMAH(rb1, Pc[0][1], bR0);
        aI0 = MFMAH(ia0, Pc[0][0], aI0); aI0 = MFMAH(ia1, Pc[0][1], aI0);
        bI0 = MFMAH(ib0, Pc[0][0], bI0); bI0 = MFMAH(ib1, Pc[0][1], bI0);
        aR1 = MFMAH(ra0, Pc[1][0], aR1); aR1 = MFMAH(ra1, Pc[1][1], aR1);
        bR1 = MFMAH(rb0, Pc[1][0], bR1); bR1 = MFMAH(rb1, Pc[1][1], bR1);
        aI1 = MFMAH(ia0, Pc[1][0], aI1); aI1 = MFMAH(ia1, Pc[1][1], aI1);
        bI1 = MFMAH(ib0, Pc[1][0], bI1); bI1 = MFMAH(ib1, Pc[1][1], bI1);

        // spin select + RTNE repack + predicated write, both chains
        const int bp1 = 2 * t + 1, bp2 = 2 * t + 2;
        #pragma unroll
        for (int r = 0; r < 4; ++r) {
            {   // chain 0: rows lg*4+r
                const unsigned w1 = (bp1 < 32) ? em0a[r] : em1a[r];
                const unsigned w2 = (bp2 < 32) ? em0a[r] : em1a[r];
                const int s1b = (int)((w1 >> (bp1 & 31)) & 1u);
                const int s2b = (int)((w2 >> (bp2 & 31)) & 1u);
                const float wr = s1b ? aR1[r] : aR0[r];
                const float wi = s1b ? aI1[r] : aI0[r];
                if (s2b == cg) {
                    Vout[(lg * 4 + r) * 36 + qjc] = pk_rtne(wr, wi);
                }
            }
            {   // chain 1: rows 16+lg*4+r
                const unsigned w1 = (bp1 < 32) ? em0b[r] : em1b[r];
                const unsigned w2 = (bp2 < 32) ? em0b[r] : em1b[r];
                const int s1b = (int)((w1 >> (bp1 & 31)) & 1u);
                const int s2b = (int)((w2 >> (bp2 & 31)) & 1u);
                const float wr = s1b ? bR1[r] : bR0[r];
                const float wi = s1b ? bI1[r] : bI0[r];
                if (s2b == cg) {
                    Vout[(16 + lg * 4 + r) * 36 + qjc] = pk_rtne(wr, wi);
                }
            }
        }
        // lgkm-only barrier: v exchange visible; VMEM stays in flight
        asm volatile("s_waitcnt lgkmcnt(0)" ::: "memory");
        __builtin_amdgcn_s_barrier();
        __builtin_amdgcn_sched_barrier(0);
    };

    #pragma unroll 1
    for (int tt = 0; tt < 15; ++tt) {
        step(2 * tt,     Vst[0], Vst[1], PA, PB);
        step(2 * tt + 1, Vst[1], Vst[0], PB, PA);
    }
    step(30, Vst[0], Vst[1], PA, PB);     // final (odd) step -> Vst[1]

    // ---- right contraction (V in Vst[1]); amp *= 2^15 (exact rescale) ----
    {
        const int e = tid & 31, jg = tid >> 5;    // jg 0..7
        const unsigned sR = (smask[e][1] >> 31) & 1u;
        const float* Rr = right_r + sR * 32;
        const float* Ri = right_i + sR * 32;
        float pr = 0.f, pi = 0.f;
        #pragma unroll
        for (int d = 0; d < 4; ++d) {
            const int j  = jg * 4 + d;
            const unsigned h = Vst[1][e * 36 + qperm(j)];
            const float vr = f16lo(h);
            const float vi = f16hi(h);
            pr += vr * Rr[j] - vi * Ri[j];
            pi += vr * Ri[j] + vi * Rr[j];
        }
        red[e][jg] = make_float2(pr, pi);
    }
    __syncthreads();
    if (tid < 32) {
        float2 a = red[tid][0];
        #pragma unroll
        for (int k = 1; k < 8; ++k) { a.x += red[tid][k].x; a.y += red[tid][k].y; }
        out[e0 + tid] = make_float2(a.x * 32768.0f, a.y * 32768.0f);
    }
}

// ---------------- fallback (round-4 kernel) if ws too small ----------------
typedef __attribute__((ext_vector_type(8))) short s16x8;
__device__ __forceinline__ unsigned cvt_pk_bf16(float lo, float hi) {
    unsigned r;
    asm("v_cvt_pk_bf16_f32 %0, %1, %2" : "=v"(r) : "v"(lo), "v"(hi));
    return r;
}
__device__ __forceinline__ float lo_f(unsigned h) { return __uint_as_float(h << 16); }
__device__ __forceinline__ float hi_f(unsigned h) { return __uint_as_float(h & 0xFFFF0000u); }
__device__ __forceinline__ s16x8 frg(u32x4 x) { return __builtin_bit_cast(s16x8, x); }
#define MFMA16(A, B, C) __builtin_amdgcn_mfma_f32_16x16x32_bf16(frg(A), frg(B), C, 0, 0, 0)

__global__ __launch_bounds__(256, 1) void mps_mfma_kernel_fb(
    const int*   __restrict__ spin,
    const float* __restrict__ left_r,  const float* __restrict__ left_i,
    const float* __restrict__ bulk_r,  const float* __restrict__ bulk_i,
    const float* __restrict__ right_r, const float* __restrict__ right_i,
    float2*      __restrict__ out)
{
    __shared__ unsigned short Bf[2][2][2][2][4][32][8];
    __shared__ float vT[2][64][33];
    __shared__ float2 red[32][8];
    __shared__ unsigned smask[32][2];

    const int tid  = threadIdx.x;
    const int l    = tid & 63;
    const int wid  = tid >> 6;
    const int mt   = wid >> 1;
    const int nt   = wid & 1;
    const int lr16 = l & 15;
    const int lg   = l >> 4;
    const int ve   = mt * 16 + lr16;
    const int jc   = nt * 16 + lr16;
    const int blk  = blockIdx.x;
    const int ccol = tid & 31;
    const int c0   = tid >> 5;

    auto convert = [&](int site, int buf) {
        const float* br = bulk_r + (size_t)site * 2048 + ccol;
        const float* bi = bulk_i + (size_t)site * 2048 + ccol;
        #pragma unroll
        for (int h = 0; h < 2; ++h) {
            const int c  = c0 + h * 8;
            const int s  = c >> 3;
            const int kk = (c >> 2) & 1;
            const int g  = c & 3;
            const int ub = kk * 16 + 2 * g;
            const float* R = br + s * 1024;
            const float* I = bi + s * 1024;
            float v0 = R[(ub + 0) * 32], v1 = I[(ub + 0) * 32];
            float v2 = R[(ub + 1) * 32], v3 = I[(ub + 1) * 32];
            float v4 = R[(ub + 8) * 32], v5 = I[(ub + 8) * 32];
            float v6 = R[(ub + 9) * 32], v7 = I[(ub + 9) * 32];
            unsigned h0 = cvt_pk_bf16(v0, v1), h1 = cvt_pk_bf16(v2, v3);
            unsigned h2 = cvt_pk_bf16(v4, v5), h3 = cvt_pk_bf16(v6, v7);
            unsigned l0 = cvt_pk_bf16(v0 - lo_f(h0), v1 - hi_f(h0));
            unsigned l1 = cvt_pk_bf16(v2 - lo_f(h1), v3 - hi_f(h1));
            unsigned l2 = cvt_pk_bf16(v4 - lo_f(h2), v5 - hi_f(h2));
            unsigned l3 = cvt_pk_bf16(v6 - lo_f(h3), v7 - hi_f(h3));
            *(u32x4*)&Bf[buf][0][s][kk][g][ccol][0] = (u32x4){h0, h1, h2, h3};
            *(u32x4*)&Bf[buf][1][s][kk][g][ccol][0] = (u32x4){l0, l1, l2, l3};
        }
    };

    if (tid < 32) {
        const int* sp = spin + ((size_t)(blk * 32 + tid)) * 64;
        unsigned a0 = 0, a1 = 0;
        #pragma unroll
        for (int k = 0; k < 32; ++k) a0 |= (unsigned)(sp[k] & 1) << k;
        #pragma unroll
        for (int k = 0; k < 32; ++k) a1 |= (unsigned)(sp[32 + k] & 1) << k;
        smask[tid][0] = a0; smask[tid][1] = a1;
    }
    {
        const int e = tid & 31, jg = tid >> 5;
        const int s0 = spin[((size_t)(blk * 32 + e)) * 64] & 1;
        #pragma unroll
        for (int d = 0; d < 4; ++d) {
            const int j = jg * 4 + d;
            vT[0][2 * j    ][e] = left_r[s0 * 32 + j];
            vT[0][2 * j + 1][e] = left_i[s0 * 32 + j];
        }
    }
    convert(0, 0);
    __syncthreads();

    unsigned em0[4], em1[4];
    #pragma unroll
    for (int r = 0; r < 4; ++r) {
        const int ee = mt * 16 + lg * 4 + r;
        em0[r] = smask[ee][0];
        em1[r] = smask[ee][1];
    }

    #pragma unroll 2
    for (int t = 0; t < 62; ++t) {
        const int b = t & 1;
        float f[16];
        #pragma unroll
        for (int kk = 0; kk < 2; ++kk)
            #pragma unroll
            for (int q = 0; q < 2; ++q)
                #pragma unroll
                for (int r = 0; r < 4; ++r)
                    f[kk * 8 + q * 4 + r] = vT[b][kk * 32 + q * 16 + 4 * lg + r][ve];

        u32x4 Vh[2], Vl[2];
        #pragma unroll
        for (int kk = 0; kk < 2; ++kk)
            #pragma unroll
            for (int q = 0; q < 2; ++q) {
                const float a = f[kk*8+q*4+0], c2 = f[kk*8+q*4+1];
                const float d2 = f[kk*8+q*4+2], e2 = f[kk*8+q*4+3];
                const unsigned h0 = cvt_pk_bf16(a, c2);
                const unsigned h1 = cvt_pk_bf16(d2, e2);
                Vh[kk][q*2+0] = h0;
                Vh[kk][q*2+1] = h1;
                Vl[kk][q*2+0] = cvt_pk_bf16(a - lo_f(h0), c2 - hi_f(h0));
                Vl[kk][q*2+1] = cvt_pk_bf16(d2 - lo_f(h1), e2 - hi_f(h1));
            }

        u32x4 Bh[2][2], Bl[2][2];
        #pragma unroll
        for (int s = 0; s < 2; ++s)
            #pragma unroll
            for (int kk = 0; kk < 2; ++kk) {
                Bh[s][kk] = *(const u32x4*)&Bf[b][0][s][kk][lg][jc][0];
                Bl[s][kk] = *(const u32x4*)&Bf[b][1][s][kk][lg][jc][0];
            }

        if (t < 61) convert(t + 1, b ^ 1);

        f32x4 ar[2] = {{0,0,0,0},{0,0,0,0}};
        f32x4 ai[2] = {{0,0,0,0},{0,0,0,0}};
        #pragma unroll
        for (int kk = 0; kk < 2; ++kk) {
            u32x4 vh, vl;
            #pragma unroll
            for (int q = 0; q < 4; ++q) {
                vh[q] = Vh[kk][q] ^ 0x80000000u;
                vl[q] = Vl[kk][q] ^ 0x80000000u;
            }
            #pragma unroll
            for (int s = 0; s < 2; ++s) {
                ar[s] = MFMA16(vh, Bh[s][kk], ar[s]);
                ar[s] = MFMA16(vh, Bl[s][kk], ar[s]);
                ar[s] = MFMA16(vl, Bh[s][kk], ar[s]);
            }
        }
        #pragma unroll
        for (int kk = 0; kk < 2; ++kk) {
            u32x4 vh, vl;
            #pragma unroll
            for (int q = 0; q < 4; ++q) {
                vh[q] = __builtin_amdgcn_alignbit(Vh[kk][q], Vh[kk][q], 16);
                vl[q] = __builtin_amdgcn_alignbit(Vl[kk][q], Vl[kk][q], 16);
            }
            #pragma unroll
            for (int s = 0; s < 2; ++s) {
                ai[s] = MFMA16(vh, Bh[s][kk], ai[s]);
                ai[s] = MFMA16(vh, Bl[s][kk], ai[s]);
                ai[s] = MFMA16(vl, Bh[s][kk], ai[s]);
            }
        }

        const int bp = t + 1;
        #pragma unroll
        for (int r = 0; r < 4; ++r) {
            const unsigned mw = (bp < 32) ? em0[r] : em1[r];
            const bool sb = (mw >> (bp & 31)) & 1u;
            const int ee = mt * 16 + lg * 4 + r;
            vT[b ^ 1][2 * jc    ][ee] = sb ? ar[1][r] : ar[0][r];
            vT[b ^ 1][2 * jc + 1][ee] = sb ? ai[1][r] : ai[0][r];
        }
        __syncthreads();
    }

    {
        const int e = tid & 31, jg = tid >> 5;
        const unsigned sR = (smask[e][1] >> 31) & 1u;
        const float* Rr = right_r + sR * 32;
        const float* Ri = right_i + sR * 32;
        float pr = 0.f, pi = 0.f;
        #pragma unroll
        for (int d = 0; d < 4; ++d) {
            const int j = jg * 4 + d;
            const float vr = vT[0][2 * j][e], vi = vT[0][2 * j + 1][e];
            pr += vr * Rr[j] - vi * Ri[j];
            pi += vr * Ri[j] + vi * Rr[j];
        }
        red[e][jg] = make_float2(pr, pi);
    }
    __syncthreads();
    if (tid < 32) {
        float2 a = red[tid][0];
        #pragma unroll
        for (int k = 1; k < 8; ++k) { a.x += red[tid][k].x; a.y += red[tid][k].y; }
        out[blk * 32 + tid] = a;
    }
}

extern "C" void kernel_launch(void* const* d_in, const int* in_sizes, int n_in,
                              void* d_out, int out_size, void* d_ws, size_t ws_size,
                              hipStream_t stream)
{
    const int*   spin = (const int*)  d_in[0];
    const float* lr   = (const float*)d_in[1];
    const float* li   = (const float*)d_in[2];
    const float* br   = (const float*)d_in[3];
    const float* bi   = (const float*)d_in[4];
    const float* rr   = (const float*)d_in[5];
    const float* ri   = (const float*)d_in[6];
    float2* out = (float2*)d_out;

    const size_t WS_NEEDED = (size_t)31 * 16384;   // 496 KB
    if (ws_size >= WS_NEEDED) {
        unsigned* ws = (unsigned*)d_ws;
        mps_pairbuild<<<dim3(124), dim3(256), 0, stream>>>(br, bi, ws);
        mps_pair16m_kernel<<<dim3(256), dim3(256), 0, stream>>>(spin, lr, li, rr, ri, ws, out);
    } else {
        mps_mfma_kernel_fb<<<dim3(256), dim3(256), 0, stream>>>(spin, lr, li, br, bi, rr, ri, out);
    }
}

// Round 18
// 27.658 us; speedup vs baseline: 1.2482x; 1.2482x over previous
//
#include <hip/hip_runtime.h>
#include <stdint.h>

// MPS amplitude via MFMA, round 14: R13 minus per-step fixed costs.
// Delta vs R13 (proven 28.6us, absmax 256): (1) s_setprio removed (m190:
// setprio serializes lockstepped blocks sharing a CU); (2) step barriers are
// lgkm-only (s_waitcnt lgkmcnt(0) + s_barrier + sched_barrier(0) — R6's
// proven sequence) instead of __syncthreads()'s vmcnt(0) drain.
// Everything else identical: fp16 1-term P and V (RTNE), pair products with
// exact 2^-(p&1) scaling (epilogue x 2^15), 512 blocks x 256 thr, 31 steps.

typedef __attribute__((ext_vector_type(4))) float        f32x4;
typedef __attribute__((ext_vector_type(8))) _Float16     f16x8;
typedef __attribute__((ext_vector_type(4))) unsigned int u32x4;

__device__ __forceinline__ float f16lo(unsigned u) {
    return (float)__builtin_bit_cast(_Float16, (unsigned short)(u & 0xFFFFu));
}
__device__ __forceinline__ float f16hi(unsigned u) {
    return (float)__builtin_bit_cast(_Float16, (unsigned short)(u >> 16));
}
__device__ __forceinline__ unsigned pk_rtne(float a, float b) {
    unsigned short x = __builtin_bit_cast(unsigned short, (_Float16)a);
    unsigned short y = __builtin_bit_cast(unsigned short, (_Float16)b);
    return (unsigned)x | ((unsigned)y << 16);
}
__device__ __forceinline__ f16x8 frg16(u32x4 x) { return __builtin_bit_cast(f16x8, x); }
#define MFMAH(A, B, C) __builtin_amdgcn_mfma_f32_16x16x32_f16(frg16(A), frg16(B), C, 0, 0, 0)

// storage permutation: complex column u -> fragment word slot
__device__ __forceinline__ int qperm(int u) {
    return (u >> 4) * 16 + ((u >> 1) & 3) * 4 + ((u >> 3) & 1) * 2 + (u & 1);
}

// ---------------- pair-product build (one-time, 124 blocks) ----------------
// ws (u32 words): pair stride 4096 (16KB). word at p*4096 + c*1024 + off,
// off = kk*512 + g*128 + col*4 + q, matrix row i = kk*16 + 2g + (q&1) + 8*(q>>1).
__global__ __launch_bounds__(256, 1) void mps_pairbuild(
    const float* __restrict__ bulk_r, const float* __restrict__ bulk_i,
    unsigned* __restrict__ ws)
{
    const int bx = blockIdx.x;
    const int p  = bx >> 2;            // pair 0..30
    const int c  = bx & 3;             // combo = s1 + 2*s2
    const int s1 = c & 1, s2 = c >> 1;
    const float* A1r = bulk_r + ((size_t)(2 * p)     * 2 + s1) * 1024;
    const float* A1i = bulk_i + ((size_t)(2 * p)     * 2 + s1) * 1024;
    const float* A2r = bulk_r + ((size_t)(2 * p + 1) * 2 + s2) * 1024;
    const float* A2i = bulk_i + ((size_t)(2 * p + 1) * 2 + s2) * 1024;

    __shared__ float s1r[1024], s1i[1024], s2r[1024], s2i[1024];
    for (int k = threadIdx.x; k < 1024; k += 256) {
        s1r[k] = A1r[k]; s1i[k] = A1i[k];
        s2r[k] = A2r[k]; s2i[k] = A2i[k];
    }
    __syncthreads();

    const int i  = threadIdx.x >> 3;        // P row 0..31
    const int j0 = (threadIdx.x & 7) * 4;   // 4 output columns
    float pr[4] = {0,0,0,0}, pi[4] = {0,0,0,0};
    #pragma unroll 4
    for (int k = 0; k < 32; ++k) {
        const float ar = s1r[i * 32 + k], ai = s1i[i * 32 + k];
        #pragma unroll
        for (int d = 0; d < 4; ++d) {
            const float br = s2r[k * 32 + j0 + d], bi = s2i[k * 32 + j0 + d];
            pr[d] += ar * br - ai * bi;
            pi[d] += ar * bi + ai * br;
        }
    }

    unsigned* wsu = ws + (size_t)p * 4096 + (size_t)c * 1024;
    const int kk = i >> 4;
    const int i4 = i & 15;
    const int qq = (i4 & 1) | (((i4 >> 3) & 1) << 1);
    const int g  = (i4 >> 1) & 3;
    const float sc = (p & 1) ? 0.5f : 1.0f;   // exact 2^-(p&1)
    #pragma unroll
    for (int d = 0; d < 4; ++d) {
        const int off = kk * 512 + g * 128 + (j0 + d) * 4 + qq;
        wsu[off] = pk_rtne(pr[d] * sc, pi[d] * sc);
    }
}

// ---------------- main chain kernel (31 pair-steps) ----------------
__global__ __launch_bounds__(256) void mps_pair16t_kernel(
    const int*   __restrict__ spin,
    const float* __restrict__ left_r,  const float* __restrict__ left_i,
    const float* __restrict__ right_r, const float* __restrict__ right_i,
    const unsigned* __restrict__ ws,
    float2*      __restrict__ out)
{
    __shared__ unsigned Vst[2][16 * 36];   // [buf][e*36 + slot], slot 0..31
    __shared__ float2 red[16][8];
    __shared__ unsigned smask[16][2];

    const int tid  = threadIdx.x;
    const int l    = tid & 63;
    const int wid  = tid >> 6;            // 0..3
    const int nt   = wid >> 1;            // column half
    const int cg   = wid & 1;             // s2 value this wave owns
    const int lr16 = l & 15;
    const int lg   = l >> 4;
    const int jc   = nt * 16 + lr16;      // C column (j)
    const int qjc  = qperm(jc);
    const int e0   = blockIdx.x * 16;

    // ---- spin masks (16 elements) ----
    if (tid < 16) {
        const int* sp = spin + (size_t)(e0 + tid) * 64;
        unsigned a0 = 0, a1 = 0;
        #pragma unroll
        for (int k = 0; k < 32; ++k) a0 |= (unsigned)(sp[k] & 1) << k;
        #pragma unroll
        for (int k = 0; k < 32; ++k) a1 |= (unsigned)(sp[32 + k] & 1) << k;
        smask[tid][0] = a0; smask[tid][1] = a1;
    }

    // ---- init v = left[s0] as packed fp16 (q-permuted) ----
    {
        const int e  = tid & 15;
        const int j0 = (tid >> 4) * 2;    // 0..30
        const int s0 = spin[(size_t)(e0 + e) * 64] & 1;
        #pragma unroll
        for (int d = 0; d < 2; ++d) {
            const int j  = j0 + d;
            const int qj = qperm(j);
            Vst[0][e * 36 + qj] = pk_rtne(left_r[s0 * 32 + j], left_i[s0 * 32 + j]);
        }
    }

    // ---- issue pair-0 P-fragment loads: P[s1][kk] ----
    const unsigned* pbw = ws + (size_t)(2 * cg) * 1024 + lg * 128 + jc * 4;
    u32x4 PA[2][2], PB[2][2];
    #pragma unroll
    for (int s1 = 0; s1 < 2; ++s1)
        #pragma unroll
        for (int kk = 0; kk < 2; ++kk)
            PA[s1][kk] = *(const u32x4*)(pbw + s1 * 1024 + kk * 512);

    __syncthreads();

    // per-lane spin words for its 4 C-row elements (rows lg*4+r)
    unsigned em0[4], em1[4];
    #pragma unroll
    for (int r = 0; r < 4; ++r) {
        em0[r] = smask[lg * 4 + r][0];
        em1[r] = smask[lg * 4 + r][1];
    }

    auto step = [&](int t, const unsigned* Vin, unsigned* Vout,
                    u32x4 (&Pc)[2][2], u32x4 (&Pn)[2][2]) {
        // prefetch next pair's P fragments (may stay in flight across barrier)
        {
            int tn = t + 1; if (tn > 30) tn = 30;
            const unsigned* pb = ws + (size_t)tn * 4096 + (size_t)(2 * cg) * 1024
                               + lg * 128 + jc * 4;
            #pragma unroll
            for (int s1 = 0; s1 < 2; ++s1)
                #pragma unroll
                for (int kk = 0; kk < 2; ++kk)
                    Pn[s1][kk] = *(const u32x4*)(pb + s1 * 1024 + kk * 512);
        }

        // V fragment reads (2 x ds_read_b128)
        const unsigned* pv = Vin + lr16 * 36 + 4 * lg;
        u32x4 Vh0 = *(const u32x4*)(pv);
        u32x4 Vh1 = *(const u32x4*)(pv + 16);

        // derive V_r = (vr,-vi) and V_i = (vi,vr)
        u32x4 r_h0, r_h1, i_h0, i_h1;
        #pragma unroll
        for (int q = 0; q < 4; ++q) {
            r_h0[q] = Vh0[q] ^ 0x80000000u;
            r_h1[q] = Vh1[q] ^ 0x80000000u;
            i_h0[q] = __builtin_amdgcn_alignbit(Vh0[q], Vh0[q], 16);
            i_h1[q] = __builtin_amdgcn_alignbit(Vh1[q], Vh1[q], 16);
        }

        // 8 MFMAs: both s1-combos x 2 kk x {R,I}
        f32x4 aR0 = {0.f,0.f,0.f,0.f}, aI0 = {0.f,0.f,0.f,0.f};
        f32x4 aR1 = {0.f,0.f,0.f,0.f}, aI1 = {0.f,0.f,0.f,0.f};
        aR0 = MFMAH(r_h0, Pc[0][0], aR0); aR0 = MFMAH(r_h1, Pc[0][1], aR0);
        aI0 = MFMAH(i_h0, Pc[0][0], aI0); aI0 = MFMAH(i_h1, Pc[0][1], aI0);
        aR1 = MFMAH(r_h0, Pc[1][0], aR1); aR1 = MFMAH(r_h1, Pc[1][1], aR1);
        aI1 = MFMAH(i_h0, Pc[1][0], aI1); aI1 = MFMAH(i_h1, Pc[1][1], aI1);

        // spin select: s1 picks combo (cndmask), s2 picks writing wave
        const int bp1 = 2 * t + 1, bp2 = 2 * t + 2;
        #pragma unroll
        for (int r = 0; r < 4; ++r) {
            const unsigned w1 = (bp1 < 32) ? em0[r] : em1[r];
            const unsigned w2 = (bp2 < 32) ? em0[r] : em1[r];
            const int s1b = (int)((w1 >> (bp1 & 31)) & 1u);
            const int s2b = (int)((w2 >> (bp2 & 31)) & 1u);
            const float wr = s1b ? aR1[r] : aR0[r];
            const float wi = s1b ? aI1[r] : aI0[r];
            if (s2b == cg) {
                const int ee = lg * 4 + r;
                Vout[ee * 36 + qjc] = pk_rtne(wr, wi);
            }
        }
        // lgkm-only barrier: v exchange visible; VMEM stays in flight
        asm volatile("s_waitcnt lgkmcnt(0)" ::: "memory");
        __builtin_amdgcn_s_barrier();
        __builtin_amdgcn_sched_barrier(0);
    };

    #pragma unroll 1
    for (int tt = 0; tt < 15; ++tt) {
        step(2 * tt,     Vst[0], Vst[1], PA, PB);
        step(2 * tt + 1, Vst[1], Vst[0], PB, PA);
    }
    step(30, Vst[0], Vst[1], PA, PB);     // final (odd) step -> Vst[1]

    // ---- right contraction (V in Vst[1]); amp *= 2^15 (exact rescale) ----
    if (tid < 128) {
        const int e = tid & 15, jg = tid >> 4;    // jg 0..7
        const unsigned sR = (smask[e][1] >> 31) & 1u;
        const float* Rr = right_r + sR * 32;
        const float* Ri = right_i + sR * 32;
        float pr = 0.f, pi = 0.f;
        #pragma unroll
        for (int d = 0; d < 4; ++d) {
            const int j  = jg * 4 + d;
            const unsigned h = Vst[1][e * 36 + qperm(j)];
            const float vr = f16lo(h);
            const float vi = f16hi(h);
            pr += vr * Rr[j] - vi * Ri[j];
            pi += vr * Ri[j] + vi * Rr[j];
        }
        red[e][jg] = make_float2(pr, pi);
    }
    __syncthreads();
    if (tid < 16) {
        float2 a = red[tid][0];
        #pragma unroll
        for (int k = 1; k < 8; ++k) { a.x += red[tid][k].x; a.y += red[tid][k].y; }
        out[e0 + tid] = make_float2(a.x * 32768.0f, a.y * 32768.0f);
    }
}

// ---------------- fallback (round-4 kernel) if ws too small ----------------
typedef __attribute__((ext_vector_type(8))) short s16x8;
__device__ __forceinline__ unsigned cvt_pk_bf16(float lo, float hi) {
    unsigned r;
    asm("v_cvt_pk_bf16_f32 %0, %1, %2" : "=v"(r) : "v"(lo), "v"(hi));
    return r;
}
__device__ __forceinline__ float lo_f(unsigned h) { return __uint_as_float(h << 16); }
__device__ __forceinline__ float hi_f(unsigned h) { return __uint_as_float(h & 0xFFFF0000u); }
__device__ __forceinline__ s16x8 frg(u32x4 x) { return __builtin_bit_cast(s16x8, x); }
#define MFMA16(A, B, C) __builtin_amdgcn_mfma_f32_16x16x32_bf16(frg(A), frg(B), C, 0, 0, 0)

__global__ __launch_bounds__(256, 1) void mps_mfma_kernel_fb(
    const int*   __restrict__ spin,
    const float* __restrict__ left_r,  const float* __restrict__ left_i,
    const float* __restrict__ bulk_r,  const float* __restrict__ bulk_i,
    const float* __restrict__ right_r, const float* __restrict__ right_i,
    float2*      __restrict__ out)
{
    __shared__ unsigned short Bf[2][2][2][2][4][32][8];
    __shared__ float vT[2][64][33];
    __shared__ float2 red[32][8];
    __shared__ unsigned smask[32][2];

    const int tid  = threadIdx.x;
    const int l    = tid & 63;
    const int wid  = tid >> 6;
    const int mt   = wid >> 1;
    const int nt   = wid & 1;
    const int lr16 = l & 15;
    const int lg   = l >> 4;
    const int ve   = mt * 16 + lr16;
    const int jc   = nt * 16 + lr16;
    const int blk  = blockIdx.x;
    const int ccol = tid & 31;
    const int c0   = tid >> 5;

    auto convert = [&](int site, int buf) {
        const float* br = bulk_r + (size_t)site * 2048 + ccol;
        const float* bi = bulk_i + (size_t)site * 2048 + ccol;
        #pragma unroll
        for (int h = 0; h < 2; ++h) {
            const int c  = c0 + h * 8;
            const int s  = c >> 3;
            const int kk = (c >> 2) & 1;
            const int g  = c & 3;
            const int ub = kk * 16 + 2 * g;
            const float* R = br + s * 1024;
            const float* I = bi + s * 1024;
            float v0 = R[(ub + 0) * 32], v1 = I[(ub + 0) * 32];
            float v2 = R[(ub + 1) * 32], v3 = I[(ub + 1) * 32];
            float v4 = R[(ub + 8) * 32], v5 = I[(ub + 8) * 32];
            float v6 = R[(ub + 9) * 32], v7 = I[(ub + 9) * 32];
            unsigned h0 = cvt_pk_bf16(v0, v1), h1 = cvt_pk_bf16(v2, v3);
            unsigned h2 = cvt_pk_bf16(v4, v5), h3 = cvt_pk_bf16(v6, v7);
            unsigned l0 = cvt_pk_bf16(v0 - lo_f(h0), v1 - hi_f(h0));
            unsigned l1 = cvt_pk_bf16(v2 - lo_f(h1), v3 - hi_f(h1));
            unsigned l2 = cvt_pk_bf16(v4 - lo_f(h2), v5 - hi_f(h2));
            unsigned l3 = cvt_pk_bf16(v6 - lo_f(h3), v7 - hi_f(h3));
            *(u32x4*)&Bf[buf][0][s][kk][g][ccol][0] = (u32x4){h0, h1, h2, h3};
            *(u32x4*)&Bf[buf][1][s][kk][g][ccol][0] = (u32x4){l0, l1, l2, l3};
        }
    };

    if (tid < 32) {
        const int* sp = spin + ((size_t)(blk * 32 + tid)) * 64;
        unsigned a0 = 0, a1 = 0;
        #pragma unroll
        for (int k = 0; k < 32; ++k) a0 |= (unsigned)(sp[k] & 1) << k;
        #pragma unroll
        for (int k = 0; k < 32; ++k) a1 |= (unsigned)(sp[32 + k] & 1) << k;
        smask[tid][0] = a0; smask[tid][1] = a1;
    }
    {
        const int e = tid & 31, jg = tid >> 5;
        const int s0 = spin[((size_t)(blk * 32 + e)) * 64] & 1;
        #pragma unroll
        for (int d = 0; d < 4; ++d) {
            const int j = jg * 4 + d;
            vT[0][2 * j    ][e] = left_r[s0 * 32 + j];
            vT[0][2 * j + 1][e] = left_i[s0 * 32 + j];
        }
    }
    convert(0, 0);
    __syncthreads();

    unsigned em0[4], em1[4];
    #pragma unroll
    for (int r = 0; r < 4; ++r) {
        const int ee = mt * 16 + lg * 4 + r;
        em0[r] = smask[ee][0];
        em1[r] = smask[ee][1];
    }

    #pragma unroll 2
    for (int t = 0; t < 62; ++t) {
        const int b = t & 1;
        float f[16];
        #pragma unroll
        for (int kk = 0; kk < 2; ++kk)
            #pragma unroll
            for (int q = 0; q < 2; ++q)
                #pragma unroll
                for (int r = 0; r < 4; ++r)
                    f[kk * 8 + q * 4 + r] = vT[b][kk * 32 + q * 16 + 4 * lg + r][ve];

        u32x4 Vh[2], Vl[2];
        #pragma unroll
        for (int kk = 0; kk < 2; ++kk)
            #pragma unroll
            for (int q = 0; q < 2; ++q) {
                const float a = f[kk*8+q*4+0], c2 = f[kk*8+q*4+1];
                const float d2 = f[kk*8+q*4+2], e2 = f[kk*8+q*4+3];
                const unsigned h0 = cvt_pk_bf16(a, c2);
                const unsigned h1 = cvt_pk_bf16(d2, e2);
                Vh[kk][q*2+0] = h0;
                Vh[kk][q*2+1] = h1;
                Vl[kk][q*2+0] = cvt_pk_bf16(a - lo_f(h0), c2 - hi_f(h0));
                Vl[kk][q*2+1] = cvt_pk_bf16(d2 - lo_f(h1), e2 - hi_f(h1));
            }

        u32x4 Bh[2][2], Bl[2][2];
        #pragma unroll
        for (int s = 0; s < 2; ++s)
            #pragma unroll
            for (int kk = 0; kk < 2; ++kk) {
                Bh[s][kk] = *(const u32x4*)&Bf[b][0][s][kk][lg][jc][0];
                Bl[s][kk] = *(const u32x4*)&Bf[b][1][s][kk][lg][jc][0];
            }

        if (t < 61) convert(t + 1, b ^ 1);

        f32x4 ar[2] = {{0,0,0,0},{0,0,0,0}};
        f32x4 ai[2] = {{0,0,0,0},{0,0,0,0}};
        #pragma unroll
        for (int kk = 0; kk < 2; ++kk) {
            u32x4 vh, vl;
            #pragma unroll
            for (int q = 0; q < 4; ++q) {
                vh[q] = Vh[kk][q] ^ 0x80000000u;
                vl[q] = Vl[kk][q] ^ 0x80000000u;
            }
            #pragma unroll
            for (int s = 0; s < 2; ++s) {
                ar[s] = MFMA16(vh, Bh[s][kk], ar[s]);
                ar[s] = MFMA16(vh, Bl[s][kk], ar[s]);
                ar[s] = MFMA16(vl, Bh[s][kk], ar[s]);
            }
        }
        #pragma unroll
        for (int kk = 0; kk < 2; ++kk) {
            u32x4 vh, vl;
            #pragma unroll
            for (int q = 0; q < 4; ++q) {
                vh[q] = __builtin_amdgcn_alignbit(Vh[kk][q], Vh[kk][q], 16);
                vl[q] = __builtin_amdgcn_alignbit(Vl[kk][q], Vl[kk][q], 16);
            }
            #pragma unroll
            for (int s = 0; s < 2; ++s) {
                ai[s] = MFMA16(vh, Bh[s][kk], ai[s]);
                ai[s] = MFMA16(vh, Bl[s][kk], ai[s]);
                ai[s] = MFMA16(vl, Bh[s][kk], ai[s]);
            }
        }

        const int bp = t + 1;
        #pragma unroll
        for (int r = 0; r < 4; ++r) {
            const unsigned mw = (bp < 32) ? em0[r] : em1[r];
            const bool sb = (mw >> (bp & 31)) & 1u;
            const int ee = mt * 16 + lg * 4 + r;
            vT[b ^ 1][2 * jc    ][ee] = sb ? ar[1][r] : ar[0][r];
            vT[b ^ 1][2 * jc + 1][ee] = sb ? ai[1][r] : ai[0][r];
        }
        __syncthreads();
    }

    {
        const int e = tid & 31, jg = tid >> 5;
        const unsigned sR = (smask[e][1] >> 31) & 1u;
        const float* Rr = right_r + sR * 32;
        const float* Ri = right_i + sR * 32;
        float pr = 0.f, pi = 0.f;
        #pragma unroll
        for (int d = 0; d < 4; ++d) {
            const int j = jg * 4 + d;
            const float vr = vT[0][2 * j][e], vi = vT[0][2 * j + 1][e];
            pr += vr * Rr[j] - vi * Ri[j];
            pi += vr * Ri[j] + vi * Rr[j];
        }
        red[e][jg] = make_float2(pr, pi);
    }
    __syncthreads();
    if (tid < 32) {
        float2 a = red[tid][0];
        #pragma unroll
        for (int k = 1; k < 8; ++k) { a.x += red[tid][k].x; a.y += red[tid][k].y; }
        out[blk * 32 + tid] = a;
    }
}

extern "C" void kernel_launch(void* const* d_in, const int* in_sizes, int n_in,
                              void* d_out, int out_size, void* d_ws, size_t ws_size,
                              hipStream_t stream)
{
    const int*   spin = (const int*)  d_in[0];
    const float* lr   = (const float*)d_in[1];
    const float* li   = (const float*)d_in[2];
    const float* br   = (const float*)d_in[3];
    const float* bi   = (const float*)d_in[4];
    const float* rr   = (const float*)d_in[5];
    const float* ri   = (const float*)d_in[6];
    float2* out = (float2*)d_out;

    const size_t WS_NEEDED = (size_t)31 * 16384;   // 496 KB
    if (ws_size >= WS_NEEDED) {
        unsigned* ws = (unsigned*)d_ws;
        mps_pairbuild<<<dim3(124), dim3(256), 0, stream>>>(br, bi, ws);
        mps_pair16t_kernel<<<dim3(512), dim3(256), 0, stream>>>(spin, lr, li, rr, ri, ws, out);
    } else {
        mps_mfma_kernel_fb<<<dim3(256), dim3(256), 0, stream>>>(spin, lr, li, br, bi, rr, ri, out);
    }
}

// Round 19
// 27.317 us; speedup vs baseline: 1.2638x; 1.0125x over previous
//
#include <hip/hip_runtime.h>
#include <stdint.h>

// MPS amplitude via MFMA, round 19: R14 main kernel (proven 27.7us, byte-
// identical) + pairbuild split into 248 blocks (2 row-halves per (p,c) job)
// so the build stage fills more of the GPU. Row-half kk=i>>4 ranges are
// disjoint in the store layout and per-output fp32 accumulation order is
// unchanged -> ws contents bit-identical to R14's.
// fp16 1-term P and V (RTNE), pair products scaled 2^-(p&1) exact
// (epilogue x 2^15), 512 blocks x 256 thr, 31 steps, lgkm-only barriers.

typedef __attribute__((ext_vector_type(4))) float        f32x4;
typedef __attribute__((ext_vector_type(8))) _Float16     f16x8;
typedef __attribute__((ext_vector_type(4))) unsigned int u32x4;

__device__ __forceinline__ float f16lo(unsigned u) {
    return (float)__builtin_bit_cast(_Float16, (unsigned short)(u & 0xFFFFu));
}
__device__ __forceinline__ float f16hi(unsigned u) {
    return (float)__builtin_bit_cast(_Float16, (unsigned short)(u >> 16));
}
__device__ __forceinline__ unsigned pk_rtne(float a, float b) {
    unsigned short x = __builtin_bit_cast(unsigned short, (_Float16)a);
    unsigned short y = __builtin_bit_cast(unsigned short, (_Float16)b);
    return (unsigned)x | ((unsigned)y << 16);
}
__device__ __forceinline__ f16x8 frg16(u32x4 x) { return __builtin_bit_cast(f16x8, x); }
#define MFMAH(A, B, C) __builtin_amdgcn_mfma_f32_16x16x32_f16(frg16(A), frg16(B), C, 0, 0, 0)

// storage permutation: complex column u -> fragment word slot
__device__ __forceinline__ int qperm(int u) {
    return (u >> 4) * 16 + ((u >> 1) & 3) * 4 + ((u >> 3) & 1) * 2 + (u & 1);
}

// ---------------- pair-product build (one-time, 248 blocks) ----------------
// ws (u32 words): pair stride 4096 (16KB). word at p*4096 + c*1024 + off,
// off = kk*512 + g*128 + col*4 + q, matrix row i = kk*16 + 2g + (q&1) + 8*(q>>1).
// Block bx: p = bx>>3, c = (bx>>1)&3, half = bx&1 -> rows [half*16, half*16+16).
__global__ __launch_bounds__(256, 1) void mps_pairbuild(
    const float* __restrict__ bulk_r, const float* __restrict__ bulk_i,
    unsigned* __restrict__ ws)
{
    const int bx   = blockIdx.x;
    const int p    = bx >> 3;           // pair 0..30
    const int c    = (bx >> 1) & 3;     // combo = s1 + 2*s2
    const int half = bx & 1;            // row half 0/1
    const int s1 = c & 1, s2 = c >> 1;
    const float* A1r = bulk_r + ((size_t)(2 * p)     * 2 + s1) * 1024 + half * 512;
    const float* A1i = bulk_i + ((size_t)(2 * p)     * 2 + s1) * 1024 + half * 512;
    const float* A2r = bulk_r + ((size_t)(2 * p + 1) * 2 + s2) * 1024;
    const float* A2i = bulk_i + ((size_t)(2 * p + 1) * 2 + s2) * 1024;

    __shared__ float s1r[512], s1i[512], s2r[1024], s2i[1024];
    for (int k = threadIdx.x; k < 512; k += 256) {
        s1r[k] = A1r[k]; s1i[k] = A1i[k];
    }
    for (int k = threadIdx.x; k < 1024; k += 256) {
        s2r[k] = A2r[k]; s2i[k] = A2i[k];
    }
    __syncthreads();

    const int il = threadIdx.x >> 4;          // local row 0..15
    const int i  = half * 16 + il;            // absolute row
    const int j0 = (threadIdx.x & 15) * 2;    // 2 output columns
    float pr[2] = {0, 0}, pi[2] = {0, 0};
    #pragma unroll 4
    for (int k = 0; k < 32; ++k) {
        const float ar = s1r[il * 32 + k], ai = s1i[il * 32 + k];
        #pragma unroll
        for (int d = 0; d < 2; ++d) {
            const float br = s2r[k * 32 + j0 + d], bi = s2i[k * 32 + j0 + d];
            pr[d] += ar * br - ai * bi;
            pi[d] += ar * bi + ai * br;
        }
    }

    unsigned* wsu = ws + (size_t)p * 4096 + (size_t)c * 1024;
    const int kk = i >> 4;
    const int i4 = i & 15;
    const int qq = (i4 & 1) | (((i4 >> 3) & 1) << 1);
    const int g  = (i4 >> 1) & 3;
    const float sc = (p & 1) ? 0.5f : 1.0f;   // exact 2^-(p&1)
    #pragma unroll
    for (int d = 0; d < 2; ++d) {
        const int off = kk * 512 + g * 128 + (j0 + d) * 4 + qq;
        wsu[off] = pk_rtne(pr[d] * sc, pi[d] * sc);
    }
}

// ---------------- main chain kernel (31 pair-steps) — R14 byte-identical ---
__global__ __launch_bounds__(256) void mps_pair16t_kernel(
    const int*   __restrict__ spin,
    const float* __restrict__ left_r,  const float* __restrict__ left_i,
    const float* __restrict__ right_r, const float* __restrict__ right_i,
    const unsigned* __restrict__ ws,
    float2*      __restrict__ out)
{
    __shared__ unsigned Vst[2][16 * 36];   // [buf][e*36 + slot], slot 0..31
    __shared__ float2 red[16][8];
    __shared__ unsigned smask[16][2];

    const int tid  = threadIdx.x;
    const int l    = tid & 63;
    const int wid  = tid >> 6;            // 0..3
    const int nt   = wid >> 1;            // column half
    const int cg   = wid & 1;             // s2 value this wave owns
    const int lr16 = l & 15;
    const int lg   = l >> 4;
    const int jc   = nt * 16 + lr16;      // C column (j)
    const int qjc  = qperm(jc);
    const int e0   = blockIdx.x * 16;

    // ---- spin masks (16 elements) ----
    if (tid < 16) {
        const int* sp = spin + (size_t)(e0 + tid) * 64;
        unsigned a0 = 0, a1 = 0;
        #pragma unroll
        for (int k = 0; k < 32; ++k) a0 |= (unsigned)(sp[k] & 1) << k;
        #pragma unroll
        for (int k = 0; k < 32; ++k) a1 |= (unsigned)(sp[32 + k] & 1) << k;
        smask[tid][0] = a0; smask[tid][1] = a1;
    }

    // ---- init v = left[s0] as packed fp16 (q-permuted) ----
    {
        const int e  = tid & 15;
        const int j0 = (tid >> 4) * 2;    // 0..30
        const int s0 = spin[(size_t)(e0 + e) * 64] & 1;
        #pragma unroll
        for (int d = 0; d < 2; ++d) {
            const int j  = j0 + d;
            const int qj = qperm(j);
            Vst[0][e * 36 + qj] = pk_rtne(left_r[s0 * 32 + j], left_i[s0 * 32 + j]);
        }
    }

    // ---- issue pair-0 P-fragment loads: P[s1][kk] ----
    const unsigned* pbw = ws + (size_t)(2 * cg) * 1024 + lg * 128 + jc * 4;
    u32x4 PA[2][2], PB[2][2];
    #pragma unroll
    for (int s1 = 0; s1 < 2; ++s1)
        #pragma unroll
        for (int kk = 0; kk < 2; ++kk)
            PA[s1][kk] = *(const u32x4*)(pbw + s1 * 1024 + kk * 512);

    __syncthreads();

    // per-lane spin words for its 4 C-row elements (rows lg*4+r)
    unsigned em0[4], em1[4];
    #pragma unroll
    for (int r = 0; r < 4; ++r) {
        em0[r] = smask[lg * 4 + r][0];
        em1[r] = smask[lg * 4 + r][1];
    }

    auto step = [&](int t, const unsigned* Vin, unsigned* Vout,
                    u32x4 (&Pc)[2][2], u32x4 (&Pn)[2][2]) {
        // prefetch next pair's P fragments (may stay in flight across barrier)
        {
            int tn = t + 1; if (tn > 30) tn = 30;
            const unsigned* pb = ws + (size_t)tn * 4096 + (size_t)(2 * cg) * 1024
                               + lg * 128 + jc * 4;
            #pragma unroll
            for (int s1 = 0; s1 < 2; ++s1)
                #pragma unroll
                for (int kk = 0; kk < 2; ++kk)
                    Pn[s1][kk] = *(const u32x4*)(pb + s1 * 1024 + kk * 512);
        }

        // V fragment reads (2 x ds_read_b128)
        const unsigned* pv = Vin + lr16 * 36 + 4 * lg;
        u32x4 Vh0 = *(const u32x4*)(pv);
        u32x4 Vh1 = *(const u32x4*)(pv + 16);

        // derive V_r = (vr,-vi) and V_i = (vi,vr)
        u32x4 r_h0, r_h1, i_h0, i_h1;
        #pragma unroll
        for (int q = 0; q < 4; ++q) {
            r_h0[q] = Vh0[q] ^ 0x80000000u;
            r_h1[q] = Vh1[q] ^ 0x80000000u;
            i_h0[q] = __builtin_amdgcn_alignbit(Vh0[q], Vh0[q], 16);
            i_h1[q] = __builtin_amdgcn_alignbit(Vh1[q], Vh1[q], 16);
        }

        // 8 MFMAs: both s1-combos x 2 kk x {R,I}
        f32x4 aR0 = {0.f,0.f,0.f,0.f}, aI0 = {0.f,0.f,0.f,0.f};
        f32x4 aR1 = {0.f,0.f,0.f,0.f}, aI1 = {0.f,0.f,0.f,0.f};
        aR0 = MFMAH(r_h0, Pc[0][0], aR0); aR0 = MFMAH(r_h1, Pc[0][1], aR0);
        aI0 = MFMAH(i_h0, Pc[0][0], aI0); aI0 = MFMAH(i_h1, Pc[0][1], aI0);
        aR1 = MFMAH(r_h0, Pc[1][0], aR1); aR1 = MFMAH(r_h1, Pc[1][1], aR1);
        aI1 = MFMAH(i_h0, Pc[1][0], aI1); aI1 = MFMAH(i_h1, Pc[1][1], aI1);

        // spin select: s1 picks combo (cndmask), s2 picks writing wave
        const int bp1 = 2 * t + 1, bp2 = 2 * t + 2;
        #pragma unroll
        for (int r = 0; r < 4; ++r) {
            const unsigned w1 = (bp1 < 32) ? em0[r] : em1[r];
            const unsigned w2 = (bp2 < 32) ? em0[r] : em1[r];
            const int s1b = (int)((w1 >> (bp1 & 31)) & 1u);
            const int s2b = (int)((w2 >> (bp2 & 31)) & 1u);
            const float wr = s1b ? aR1[r] : aR0[r];
            const float wi = s1b ? aI1[r] : aI0[r];
            if (s2b == cg) {
                const int ee = lg * 4 + r;
                Vout[ee * 36 + qjc] = pk_rtne(wr, wi);
            }
        }
        // lgkm-only barrier: v exchange visible; VMEM stays in flight
        asm volatile("s_waitcnt lgkmcnt(0)" ::: "memory");
        __builtin_amdgcn_s_barrier();
        __builtin_amdgcn_sched_barrier(0);
    };

    #pragma unroll 1
    for (int tt = 0; tt < 15; ++tt) {
        step(2 * tt,     Vst[0], Vst[1], PA, PB);
        step(2 * tt + 1, Vst[1], Vst[0], PB, PA);
    }
    step(30, Vst[0], Vst[1], PA, PB);     // final (odd) step -> Vst[1]

    // ---- right contraction (V in Vst[1]); amp *= 2^15 (exact rescale) ----
    if (tid < 128) {
        const int e = tid & 15, jg = tid >> 4;    // jg 0..7
        const unsigned sR = (smask[e][1] >> 31) & 1u;
        const float* Rr = right_r + sR * 32;
        const float* Ri = right_i + sR * 32;
        float pr = 0.f, pi = 0.f;
        #pragma unroll
        for (int d = 0; d < 4; ++d) {
            const int j  = jg * 4 + d;
            const unsigned h = Vst[1][e * 36 + qperm(j)];
            const float vr = f16lo(h);
            const float vi = f16hi(h);
            pr += vr * Rr[j] - vi * Ri[j];
            pi += vr * Ri[j] + vi * Rr[j];
        }
        red[e][jg] = make_float2(pr, pi);
    }
    __syncthreads();
    if (tid < 16) {
        float2 a = red[tid][0];
        #pragma unroll
        for (int k = 1; k < 8; ++k) { a.x += red[tid][k].x; a.y += red[tid][k].y; }
        out[e0 + tid] = make_float2(a.x * 32768.0f, a.y * 32768.0f);
    }
}

// ---------------- fallback (round-4 kernel) if ws too small ----------------
typedef __attribute__((ext_vector_type(8))) short s16x8;
__device__ __forceinline__ unsigned cvt_pk_bf16(float lo, float hi) {
    unsigned r;
    asm("v_cvt_pk_bf16_f32 %0, %1, %2" : "=v"(r) : "v"(lo), "v"(hi));
    return r;
}
__device__ __forceinline__ float lo_f(unsigned h) { return __uint_as_float(h << 16); }
__device__ __forceinline__ float hi_f(unsigned h) { return __uint_as_float(h & 0xFFFF0000u); }
__device__ __forceinline__ s16x8 frg(u32x4 x) { return __builtin_bit_cast(s16x8, x); }
#define MFMA16(A, B, C) __builtin_amdgcn_mfma_f32_16x16x32_bf16(frg(A), frg(B), C, 0, 0, 0)

__global__ __launch_bounds__(256, 1) void mps_mfma_kernel_fb(
    const int*   __restrict__ spin,
    const float* __restrict__ left_r,  const float* __restrict__ left_i,
    const float* __restrict__ bulk_r,  const float* __restrict__ bulk_i,
    const float* __restrict__ right_r, const float* __restrict__ right_i,
    float2*      __restrict__ out)
{
    __shared__ unsigned short Bf[2][2][2][2][4][32][8];
    __shared__ float vT[2][64][33];
    __shared__ float2 red[32][8];
    __shared__ unsigned smask[32][2];

    const int tid  = threadIdx.x;
    const int l    = tid & 63;
    const int wid  = tid >> 6;
    const int mt   = wid >> 1;
    const int nt   = wid & 1;
    const int lr16 = l & 15;
    const int lg   = l >> 4;
    const int ve   = mt * 16 + lr16;
    const int jc   = nt * 16 + lr16;
    const int blk  = blockIdx.x;
    const int ccol = tid & 31;
    const int c0   = tid >> 5;

    auto convert = [&](int site, int buf) {
        const float* br = bulk_r + (size_t)site * 2048 + ccol;
        const float* bi = bulk_i + (size_t)site * 2048 + ccol;
        #pragma unroll
        for (int h = 0; h < 2; ++h) {
            const int c  = c0 + h * 8;
            const int s  = c >> 3;
            const int kk = (c >> 2) & 1;
            const int g  = c & 3;
            const int ub = kk * 16 + 2 * g;
            const float* R = br + s * 1024;
            const float* I = bi + s * 1024;
            float v0 = R[(ub + 0) * 32], v1 = I[(ub + 0) * 32];
            float v2 = R[(ub + 1) * 32], v3 = I[(ub + 1) * 32];
            float v4 = R[(ub + 8) * 32], v5 = I[(ub + 8) * 32];
            float v6 = R[(ub + 9) * 32], v7 = I[(ub + 9) * 32];
            unsigned h0 = cvt_pk_bf16(v0, v1), h1 = cvt_pk_bf16(v2, v3);
            unsigned h2 = cvt_pk_bf16(v4, v5), h3 = cvt_pk_bf16(v6, v7);
            unsigned l0 = cvt_pk_bf16(v0 - lo_f(h0), v1 - hi_f(h0));
            unsigned l1 = cvt_pk_bf16(v2 - lo_f(h1), v3 - hi_f(h1));
            unsigned l2 = cvt_pk_bf16(v4 - lo_f(h2), v5 - hi_f(h2));
            unsigned l3 = cvt_pk_bf16(v6 - lo_f(h3), v7 - hi_f(h3));
            *(u32x4*)&Bf[buf][0][s][kk][g][ccol][0] = (u32x4){h0, h1, h2, h3};
            *(u32x4*)&Bf[buf][1][s][kk][g][ccol][0] = (u32x4){l0, l1, l2, l3};
        }
    };

    if (tid < 32) {
        const int* sp = spin + ((size_t)(blk * 32 + tid)) * 64;
        unsigned a0 = 0, a1 = 0;
        #pragma unroll
        for (int k = 0; k < 32; ++k) a0 |= (unsigned)(sp[k] & 1) << k;
        #pragma unroll
        for (int k = 0; k < 32; ++k) a1 |= (unsigned)(sp[32 + k] & 1) << k;
        smask[tid][0] = a0; smask[tid][1] = a1;
    }
    {
        const int e = tid & 31, jg = tid >> 5;
        const int s0 = spin[((size_t)(blk * 32 + e)) * 64] & 1;
        #pragma unroll
        for (int d = 0; d < 4; ++d) {
            const int j = jg * 4 + d;
            vT[0][2 * j    ][e] = left_r[s0 * 32 + j];
            vT[0][2 * j + 1][e] = left_i[s0 * 32 + j];
        }
    }
    convert(0, 0);
    __syncthreads();

    unsigned em0[4], em1[4];
    #pragma unroll
    for (int r = 0; r < 4; ++r) {
        const int ee = mt * 16 + lg * 4 + r;
        em0[r] = smask[ee][0];
        em1[r] = smask[ee][1];
    }

    #pragma unroll 2
    for (int t = 0; t < 62; ++t) {
        const int b = t & 1;
        float f[16];
        #pragma unroll
        for (int kk = 0; kk < 2; ++kk)
            #pragma unroll
            for (int q = 0; q < 2; ++q)
                #pragma unroll
                for (int r = 0; r < 4; ++r)
                    f[kk * 8 + q * 4 + r] = vT[b][kk * 32 + q * 16 + 4 * lg + r][ve];

        u32x4 Vh[2], Vl[2];
        #pragma unroll
        for (int kk = 0; kk < 2; ++kk)
            #pragma unroll
            for (int q = 0; q < 2; ++q) {
                const float a = f[kk*8+q*4+0], c2 = f[kk*8+q*4+1];
                const float d2 = f[kk*8+q*4+2], e2 = f[kk*8+q*4+3];
                const unsigned h0 = cvt_pk_bf16(a, c2);
                const unsigned h1 = cvt_pk_bf16(d2, e2);
                Vh[kk][q*2+0] = h0;
                Vh[kk][q*2+1] = h1;
                Vl[kk][q*2+0] = cvt_pk_bf16(a - lo_f(h0), c2 - hi_f(h0));
                Vl[kk][q*2+1] = cvt_pk_bf16(d2 - lo_f(h1), e2 - hi_f(h1));
            }

        u32x4 Bh[2][2], Bl[2][2];
        #pragma unroll
        for (int s = 0; s < 2; ++s)
            #pragma unroll
            for (int kk = 0; kk < 2; ++kk) {
                Bh[s][kk] = *(const u32x4*)&Bf[b][0][s][kk][lg][jc][0];
                Bl[s][kk] = *(const u32x4*)&Bf[b][1][s][kk][lg][jc][0];
            }

        if (t < 61) convert(t + 1, b ^ 1);

        f32x4 ar[2] = {{0,0,0,0},{0,0,0,0}};
        f32x4 ai[2] = {{0,0,0,0},{0,0,0,0}};
        #pragma unroll
        for (int kk = 0; kk < 2; ++kk) {
            u32x4 vh, vl;
            #pragma unroll
            for (int q = 0; q < 4; ++q) {
                vh[q] = Vh[kk][q] ^ 0x80000000u;
                vl[q] = Vl[kk][q] ^ 0x80000000u;
            }
            #pragma unroll
            for (int s = 0; s < 2; ++s) {
                ar[s] = MFMA16(vh, Bh[s][kk], ar[s]);
                ar[s] = MFMA16(vh, Bl[s][kk], ar[s]);
                ar[s] = MFMA16(vl, Bh[s][kk], ar[s]);
            }
        }
        #pragma unroll
        for (int kk = 0; kk < 2; ++kk) {
            u32x4 vh, vl;
            #pragma unroll
            for (int q = 0; q < 4; ++q) {
                vh[q] = __builtin_amdgcn_alignbit(Vh[kk][q], Vh[kk][q], 16);
                vl[q] = __builtin_amdgcn_alignbit(Vl[kk][q], Vl[kk][q], 16);
            }
            #pragma unroll
            for (int s = 0; s < 2; ++s) {
                ai[s] = MFMA16(vh, Bh[s][kk], ai[s]);
                ai[s] = MFMA16(vh, Bl[s][kk], ai[s]);
                ai[s] = MFMA16(vl, Bh[s][kk], ai[s]);
            }
        }

        const int bp = t + 1;
        #pragma unroll
        for (int r = 0; r < 4; ++r) {
            const unsigned mw = (bp < 32) ? em0[r] : em1[r];
            const bool sb = (mw >> (bp & 31)) & 1u;
            const int ee = mt * 16 + lg * 4 + r;
            vT[b ^ 1][2 * jc    ][ee] = sb ? ar[1][r] : ar[0][r];
            vT[b ^ 1][2 * jc + 1][ee] = sb ? ai[1][r] : ai[0][r];
        }
        __syncthreads();
    }

    {
        const int e = tid & 31, jg = tid >> 5;
        const unsigned sR = (smask[e][1] >> 31) & 1u;
        const float* Rr = right_r + sR * 32;
        const float* Ri = right_i + sR * 32;
        float pr = 0.f, pi = 0.f;
        #pragma unroll
        for (int d = 0; d < 4; ++d) {
            const int j = jg * 4 + d;
            const float vr = vT[0][2 * j][e], vi = vT[0][2 * j + 1][e];
            pr += vr * Rr[j] - vi * Ri[j];
            pi += vr * Ri[j] + vi * Rr[j];
        }
        red[e][jg] = make_float2(pr, pi);
    }
    __syncthreads();
    if (tid < 32) {
        float2 a = red[tid][0];
        #pragma unroll
        for (int k = 1; k < 8; ++k) { a.x += red[tid][k].x; a.y += red[tid][k].y; }
        out[blk * 32 + tid] = a;
    }
}

extern "C" void kernel_launch(void* const* d_in, const int* in_sizes, int n_in,
                              void* d_out, int out_size, void* d_ws, size_t ws_size,
                              hipStream_t stream)
{
    const int*   spin = (const int*)  d_in[0];
    const float* lr   = (const float*)d_in[1];
    const float* li   = (const float*)d_in[2];
    const float* br   = (const float*)d_in[3];
    const float* bi   = (const float*)d_in[4];
    const float* rr   = (const float*)d_in[5];
    const float* ri   = (const float*)d_in[6];
    float2* out = (float2*)d_out;

    const size_t WS_NEEDED = (size_t)31 * 16384;   // 496 KB
    if (ws_size >= WS_NEEDED) {
        unsigned* ws = (unsigned*)d_ws;
        mps_pairbuild<<<dim3(248), dim3(256), 0, stream>>>(br, bi, ws);
        mps_pair16t_kernel<<<dim3(512), dim3(256), 0, stream>>>(spin, lr, li, rr, ri, ws, out);
    } else {
        mps_mfma_kernel_fb<<<dim3(256), dim3(256), 0, stream>>>(spin, lr, li, br, bi, rr, ri, out);
    }
}